// Round 3
// baseline (6006.083 us; speedup 1.0000x reference)
//
#include <hip/hip_runtime.h>
#include <cstdint>
#include <cstddef>

// Problem constants
#define B_  512
#define L_  60
#define D_  300
#define H_  256
#define BT  1024          // combined batch (2 branches)
#define KX  320           // D padded to 320 (zeros in pad)
#define KL  576           // LSTM GEMM K: 320 (x) + 256 (h)
#define NG  1024          // 4*H gate width

typedef _Float16 half8   __attribute__((ext_vector_type(8)));
typedef _Float16 half4_t __attribute__((ext_vector_type(4)));
typedef float    floatx4 __attribute__((ext_vector_type(4)));

__device__ __forceinline__ float fast_tanh(float x){ float e = __expf(2.f*x); return 1.f - 2.f/(e + 1.f); }
__device__ __forceinline__ float sigm(float x){ return 1.f/(1.f + __expf(-x)); }

#define MFMA16(a,b,c) __builtin_amdgcn_mfma_f32_16x16x32_f16(a,b,c,0,0,0)

// ---------------------------------------------------------------- prep
// Gather embeddings for [input1; input2] -> X16[1024][60][320] f16 (pad zeros)
__global__ __launch_bounds__(256) void k_gather(const float* __restrict__ E,
    const int* __restrict__ in1, const int* __restrict__ in2, _Float16* __restrict__ X16)
{
    int gid = blockIdx.x*256 + threadIdx.x;
    int row = gid / (L_*40);
    int rem = gid - row*(L_*40);
    int t  = rem / 40;
    int ch = rem - t*40;
    int k0 = ch*8;
    int tok = (row < B_) ? in1[row*L_ + t] : in2[(row - B_)*L_ + t];
    const float* src = E + (size_t)tok*D_ + k0;
    half8 out;
    #pragma unroll
    for (int k = 0; k < 8; ++k) out[k] = (_Float16)0.f;
    if (k0 + 8 <= D_) {
        float4 a = *(const float4*)(src);
        float4 b = *(const float4*)(src + 4);
        out[0]=(_Float16)a.x; out[1]=(_Float16)a.y; out[2]=(_Float16)a.z; out[3]=(_Float16)a.w;
        out[4]=(_Float16)b.x; out[5]=(_Float16)b.y; out[6]=(_Float16)b.z; out[7]=(_Float16)b.w;
    } else if (k0 < D_) {
        float4 a = *(const float4*)(src);
        out[0]=(_Float16)a.x; out[1]=(_Float16)a.y; out[2]=(_Float16)a.z; out[3]=(_Float16)a.w;
    }
    *(half8*)(X16 + ((size_t)row*L_ + t)*KX + k0) = out;
}

// LSTM weights -> BcatT[set][n=1024][k=576] f16; k<300 Wx, 300..319 zero, >=320 Wh
__global__ __launch_bounds__(256) void k_prep_lstmW(const float* __restrict__ Wx1, const float* __restrict__ Wh1,
    const float* __restrict__ Wx2, const float* __restrict__ Wh2, _Float16* __restrict__ BcatT)
{
    int idx = blockIdx.x*256 + threadIdx.x;
    int set = (idx >= KL*NG) ? 1 : 0;
    int rem = idx - set*(KL*NG);
    int k = rem >> 10, n = rem & 1023;
    const float* Wx = set ? Wx2 : Wx1;
    const float* Wh = set ? Wh2 : Wh1;
    float v = 0.f;
    if (k < D_)       v = Wx[k*NG + n];
    else if (k >= KX) v = Wh[(k - KX)*NG + n];
    BcatT[((size_t)set*NG + n)*KL + k] = (_Float16)v;
}

// Attention weights f16 transposed [n][k].
// AW elem offsets: WyT@0 [256][256], WhaT@65536 [256][256],
//   WrtT@131072 [512][256] (n<256: Wr_a col n; else Wt_a col n-256),
//   WfinT@262144 [256][512] (k<256 Wp_a else Wxa). grid 1536.
__global__ __launch_bounds__(256) void k_prep_attnW(const float* __restrict__ W_y,
    const float* __restrict__ Wh_a, const float* __restrict__ Wr_a, const float* __restrict__ Wt_a,
    const float* __restrict__ Wp_a, const float* __restrict__ Wxa, _Float16* __restrict__ AW)
{
    int idx = blockIdx.x*256 + threadIdx.x;
    float v; int dst;
    if (idx < 65536) {
        int k = idx >> 8, n = idx & 255;
        v = W_y[k*256 + n];
        dst = n*256 + k;
    } else if (idx < 131072) {
        int j = idx - 65536; int k = j >> 8, n = j & 255;
        v = Wh_a[k*256 + n];
        dst = 65536 + n*256 + k;
    } else if (idx < 262144) {
        int j = idx - 131072; int n = j >> 8, k = j & 255;
        v = (n < 256) ? Wr_a[k*256 + n] : Wt_a[k*256 + (n - 256)];
        dst = 131072 + n*256 + k;
    } else {
        int j = idx - 262144; int n = j >> 9, k = j & 511;
        v = (k < 256) ? Wp_a[k*256 + n] : Wxa[(k - 256)*256 + n];
        dst = 262144 + n*512 + k;
    }
    AW[dst] = (_Float16)v;
}

// ---------------------------------------------------------------- LSTM mega-kernel
// 128 blocks, 4 waves. Block owns 16 rows for ALL 60 steps; h in LDS, c in regs.
// set = bid&1 (keeps one weight set per XCD L2); wave owns all 4 gates of its 64 h-dims
// (col = g*256 + wv*64 + hb*16 + lm) so the cell update is entirely in-lane.
__global__ __launch_bounds__(256) void k_lstm_mega(
    const _Float16* __restrict__ X16, const _Float16* __restrict__ BcatT,
    const float* __restrict__ b1, const float* __restrict__ b2,
    const int* __restrict__ s1, const int* __restrict__ s2,
    _Float16* __restrict__ Y16, _Float16* __restrict__ h2)
{
    __shared__ _Float16 sX[16*328];   // current-step x rows (k-pad to 320, stride 328)
    __shared__ _Float16 sH[16*264];   // h state, f16, stride 264
    __shared__ int      sSl[16];

    const int tid = threadIdx.x;
    const int bid = blockIdx.x;
    const int set = bid & 1;
    const int rs0 = (bid >> 1)*16;
    const int lane = tid & 63, wv = tid >> 6;
    const int q = lane >> 4, lm = lane & 15;
    const int grBase = set*1024 + rs0;

    if (tid < 16) {
        int rs = rs0 + tid;
        sSl[tid] = (set == 0) ? ((rs < B_) ? s1[rs] : s2[rs - B_])
                              : ((rs < B_) ? s2[rs] : s1[rs - B_]);
    }
    for (int i = tid; i < 16*264; i += 256) sH[i] = (_Float16)0.f;
    __syncthreads();

    // per-lane constants
    const float* bias = set ? b2 : b1;
    float bI[4], bJ[4], bF[4], bO[4];
    #pragma unroll
    for (int hb = 0; hb < 4; ++hb) {
        int h = wv*64 + hb*16 + lm;
        bI[hb] = bias[h]; bJ[hb] = bias[256 + h];
        bF[hb] = bias[512 + h]; bO[hb] = bias[768 + h];
    }
    int slr[4];
    #pragma unroll
    for (int r = 0; r < 4; ++r) slr[r] = sSl[q*4 + r];

    // B base for this lane: col = (ti&3)*256 + wv*64 + (ti>>2)*16 + lm, k offset q*8
    const _Float16* Bp = BcatT + (size_t)set*NG*KL + (wv*64 + lm)*KL + q*8;

    float creg[16];
    #pragma unroll
    for (int i = 0; i < 16; ++i) creg[i] = 0.f;

    for (int t = 0; t < L_; ++t) {
        // stage x rows for this step
        for (int ci = tid; ci < 640; ci += 256) {
            int row = ci / 40, kg = (ci - row*40)*8;
            int rs = rs0 + row;
            int xrow = set ? ((rs + 512) & 1023) : rs;
            *(half8*)(sX + row*328 + kg) = *(const half8*)(X16 + ((size_t)xrow*L_ + t)*KX + kg);
        }
        __syncthreads();

        floatx4 acc[16];
        #pragma unroll
        for (int i = 0; i < 16; ++i) acc[i] = (floatx4){0.f,0.f,0.f,0.f};

        for (int ch = 0; ch < 18; ++ch) {
            half8 a = (ch < 10) ? *(const half8*)(sX + lm*328 + ch*32 + q*8)
                                : *(const half8*)(sH + lm*264 + (ch-10)*32 + q*8);
            half8 b[16];
            #pragma unroll
            for (int ti = 0; ti < 16; ++ti)
                b[ti] = *(const half8*)(Bp + ((ti&3)*256 + (ti>>2)*16)*KL + ch*32);
            #pragma unroll
            for (int ti = 0; ti < 16; ++ti) acc[ti] = MFMA16(a, b[ti], acc[ti]);
        }
        __syncthreads();   // all waves done reading sH before update writes it

        // in-lane cell update: acc[hb*4+g][r] holds gate g, h-dim wv*64+hb*16+lm, row q*4+r
        #pragma unroll
        for (int hb = 0; hb < 4; ++hb) {
            int h = wv*64 + hb*16 + lm;
            #pragma unroll
            for (int r = 0; r < 4; ++r) {
                float gi = acc[hb*4+0][r] + bI[hb];
                float gj = acc[hb*4+1][r] + bJ[hb];
                float gf = acc[hb*4+2][r] + bF[hb];
                float go = acc[hb*4+3][r] + bO[hb];
                float c_new = creg[hb*4+r]*sigm(gf + 1.f) + sigm(gi)*fast_tanh(gj);
                float h_new = fast_tanh(c_new)*sigm(go);
                bool act = (t < slr[r]);
                if (act) {
                    creg[hb*4+r] = c_new;
                    sH[(q*4+r)*264 + h] = (_Float16)h_new;
                }
                int gr = grBase + q*4 + r;
                Y16[((size_t)gr*L_ + t)*H_ + h] = act ? (_Float16)h_new : (_Float16)0.f;
            }
        }
        __syncthreads();
    }

    if (set == 1)
        for (int i = 0; i < 16; ++i)
            h2[(size_t)(rs0 + i)*H_ + tid] = sH[i*264 + tid];
}

// ---------------------------------------------------------------- WyY / TH precompute
// z=0: WyY = Y16[set0] @ WyT ; z=1: TH = Y16[set1] @ WhaT. M=61440, N=256, K=256.
// grid (4, 960, 2)
__global__ __launch_bounds__(256) void k_wyyth(const _Float16* __restrict__ Y16,
    const _Float16* __restrict__ AW, _Float16* __restrict__ WyY16, _Float16* __restrict__ TH16)
{
    __shared__ _Float16 sA[64*40];
    __shared__ _Float16 sB[64*40];
    const int tid = threadIdx.x;
    const int n0 = blockIdx.x*64, m0 = blockIdx.y*64, z = blockIdx.z;
    const int lane = tid & 63, wv = tid >> 6;
    const int wm = (wv & 1)*32, wn = (wv >> 1)*32;
    const int q = lane >> 4, lm = lane & 15;
    const int am = tid >> 2, kg = (tid & 3)*8;
    const _Float16* aRow = Y16 + (size_t)z*15728640 + (size_t)(m0 + am)*H_;
    const _Float16* bRow = AW + (size_t)z*65536 + (size_t)(n0 + am)*H_;
    _Float16* dst = z ? TH16 : WyY16;
    floatx4 acc00 = {0.f,0.f,0.f,0.f}, acc01 = acc00, acc10 = acc00, acc11 = acc00;
    half8 av = *(const half8*)(aRow + kg);
    half8 bv = *(const half8*)(bRow + kg);
    for (int ch = 0; ch < 8; ++ch) {
        __syncthreads();
        *(half8*)(sA + am*40 + kg) = av;
        *(half8*)(sB + am*40 + kg) = bv;
        __syncthreads();
        if (ch < 7) {
            av = *(const half8*)(aRow + (ch+1)*32 + kg);
            bv = *(const half8*)(bRow + (ch+1)*32 + kg);
        }
        half8 a0v = *(const half8*)(sA + (wm + lm)*40 + q*8);
        half8 a1v = *(const half8*)(sA + (wm + 16 + lm)*40 + q*8);
        half8 b0v = *(const half8*)(sB + (wn + lm)*40 + q*8);
        half8 b1v = *(const half8*)(sB + (wn + 16 + lm)*40 + q*8);
        acc00 = MFMA16(a0v, b0v, acc00); acc01 = MFMA16(a0v, b1v, acc01);
        acc10 = MFMA16(a1v, b0v, acc10); acc11 = MFMA16(a1v, b1v, acc11);
    }
    int rb = m0 + wm + q*4, col = n0 + wn + lm;
    #pragma unroll
    for (int r = 0; r < 4; ++r) {
        dst[(size_t)(rb + r)*H_ + col]           = (_Float16)acc00[r];
        dst[(size_t)(rb + r)*H_ + col + 16]      = (_Float16)acc01[r];
        dst[(size_t)(rb + 16 + r)*H_ + col]      = (_Float16)acc10[r];
        dst[(size_t)(rb + 16 + r)*H_ + col + 16] = (_Float16)acc11[r];
    }
}

// ---------------------------------------------------------------- attention mega-kernel
// 128 blocks, 4 waves; block owns 8 rows for ALL 60 steps. r in LDS (16-row MFMA A-tile,
// rows 8-15 zero). Per step: rGEMM r@[Wr|Wt] (K=256) -> sW; logits over l<sAtt with exact
// mask skip; softmax; r update with dead-row (t>=sCap) skip.
__global__ __launch_bounds__(256) void k_attn_mega(
    const _Float16* __restrict__ Y16, const _Float16* __restrict__ WyY16,
    const _Float16* __restrict__ TH16, const _Float16* __restrict__ AW,
    const float* __restrict__ w_a, _Float16* __restrict__ rL16,
    const int* __restrict__ s1, const int* __restrict__ s2)
{
    __shared__ _Float16 sR[16*264];
    __shared__ float sW[8*520];      // cols 0-255: r@Wr_a, 256-511: r@Wt_a
    __shared__ float sTW[8*264];     // TH[u][t][:] + r@Wr_a
    __shared__ float sLog[8*64];
    __shared__ float sAl[8*64];
    __shared__ float sWa[256];
    __shared__ int   sAtt[8], sCap[8];

    const int tid = threadIdx.x;
    const int u0 = blockIdx.x*8;
    const int lane = tid & 63, wv = tid >> 6;
    const int q = lane >> 4, lm = lane & 15;

    if (tid < 8) {
        int u = u0 + tid;
        if (u < B_) { sCap[tid] = s2[u];      sAtt[tid] = s1[u]; }
        else        { sCap[tid] = s1[u - B_]; sAtt[tid] = s2[u - B_]; }
    }
    sWa[tid] = w_a[tid];
    for (int i = tid; i < 16*264; i += 256) sR[i] = (_Float16)0.f;

    const _Float16* WrtT = AW + 131072;
    const _Float16* Bp = WrtT + (wv*128 + lm)*256 + q*8;

    for (int t = 0; t < L_; ++t) {
        __syncthreads();   // sR writes (prev step) -> rGEMM reads

        // rGEMM: wave wv covers cols [wv*128, wv*128+128)
        floatx4 acc[8];
        #pragma unroll
        for (int i = 0; i < 8; ++i) acc[i] = (floatx4){0.f,0.f,0.f,0.f};
        for (int ch = 0; ch < 8; ++ch) {
            half8 a = *(const half8*)(sR + lm*264 + ch*32 + q*8);
            half8 b[8];
            #pragma unroll
            for (int ti = 0; ti < 8; ++ti)
                b[ti] = *(const half8*)(Bp + ti*16*256 + ch*32);
            #pragma unroll
            for (int ti = 0; ti < 8; ++ti) acc[ti] = MFMA16(a, b[ti], acc[ti]);
        }
        if (q < 2) {
            #pragma unroll
            for (int ti = 0; ti < 8; ++ti) {
                int col = wv*128 + ti*16 + lm;
                #pragma unroll
                for (int r = 0; r < 4; ++r)
                    sW[(q*4+r)*520 + col] = acc[ti][r];
            }
        }
        __syncthreads();

        // sTW = TH[u][t][:] + rWr
        #pragma unroll
        for (int i = 0; i < 8; ++i)
            sTW[i*264 + tid] = (float)TH16[((size_t)(u0+i)*L_ + t)*H_ + tid] + sW[i*520 + tid];
        __syncthreads();

        // logits: wave wv handles rows {2wv, 2wv+1}
        #pragma unroll
        for (int rr = 0; rr < 2; ++rr) {
            int i = wv*2 + rr;
            if (t < sCap[i]) {
                int sa = sAtt[i];
                const _Float16* wy = WyY16 + ((size_t)(u0+i)*L_)*H_ + lane*4;
                for (int l = 0; l < sa; ++l) {
                    half4_t yv = *(const half4_t*)(wy + l*H_);
                    float v = 0.f;
                    #pragma unroll
                    for (int k = 0; k < 4; ++k)
                        v += fast_tanh((float)yv[k] + sTW[i*264 + lane*4 + k]) * sWa[lane*4 + k];
                    #pragma unroll
                    for (int off = 32; off > 0; off >>= 1) v += __shfl_down(v, off);
                    if (lane == 0) sLog[i*64 + l] = v;
                }
            }
        }
        __syncthreads();

        // softmax per row
        #pragma unroll
        for (int rr = 0; rr < 2; ++rr) {
            int i = wv*2 + rr;
            if (t < sCap[i]) {
                int sa = sAtt[i];
                float x = (lane < sa) ? sLog[i*64 + lane] : -3.4e38f;
                float m = x;
                #pragma unroll
                for (int off = 32; off > 0; off >>= 1) m = fmaxf(m, __shfl_xor(m, off));
                float e = (lane < sa) ? __expf(x - m) : 0.f;
                float s = e;
                #pragma unroll
                for (int off = 32; off > 0; off >>= 1) s += __shfl_xor(s, off);
                sAl[i*64 + lane] = e / s;
            }
        }
        __syncthreads();

        // r update: 2 passes x 4 rows; thread handles 4 h via half4
        #pragma unroll
        for (int p = 0; p < 2; ++p) {
            int i = p*4 + wv;
            if (t < sCap[i]) {
                int h4 = lane*4;
                int sa = sAtt[i];
                const _Float16* yb = Y16 + ((size_t)(u0+i)*L_)*H_ + h4;
                float a0=0.f, a1=0.f, a2=0.f, a3=0.f;
                for (int l = 0; l < sa; ++l) {
                    float al = sAl[i*64 + l];
                    half4_t yv = *(const half4_t*)(yb + l*H_);
                    a0 += al*(float)yv[0]; a1 += al*(float)yv[1];
                    a2 += al*(float)yv[2]; a3 += al*(float)yv[3];
                }
                half4_t out;
                out[0] = (_Float16)(a0 + fast_tanh(sW[i*520 + 256 + h4]));
                out[1] = (_Float16)(a1 + fast_tanh(sW[i*520 + 257 + h4]));
                out[2] = (_Float16)(a2 + fast_tanh(sW[i*520 + 258 + h4]));
                out[3] = (_Float16)(a3 + fast_tanh(sW[i*520 + 259 + h4]));
                *(half4_t*)(sR + i*264 + h4) = out;
                if (t == sCap[i] - 1)
                    *(half4_t*)(rL16 + (size_t)(u0+i)*H_ + h4) = out;
            }
        }
    }
}

// ---------------------------------------------------------------- ff = [rL | h2] @ (Wp_a|Wxa)
__global__ __launch_bounds__(256) void k_final_gemm(const _Float16* __restrict__ rL16,
    const _Float16* __restrict__ h2, const _Float16* __restrict__ WfinT, float* __restrict__ ff)
{
    __shared__ _Float16 sA[64*40];
    __shared__ _Float16 sB[64*40];
    const int tid = threadIdx.x;
    const int n0 = blockIdx.x*64, m0 = blockIdx.y*64;
    const int lane = tid & 63, wv = tid >> 6;
    const int wm = (wv & 1)*32, wn = (wv >> 1)*32;
    const int q = lane >> 4, lm = lane & 15;
    const int am = tid >> 2, kg = (tid & 3)*8;
    const int row = m0 + am;
    const _Float16* bRow = WfinT + (size_t)(n0 + am)*512;
    floatx4 acc00 = {0.f,0.f,0.f,0.f}, acc01 = acc00, acc10 = acc00, acc11 = acc00;
    for (int ch = 0; ch < 16; ++ch) {
        const int k0 = ch*32;
        half8 av = (k0 < 256) ? *(const half8*)(rL16 + (size_t)row*H_ + k0 + kg)
                              : *(const half8*)(h2   + (size_t)row*H_ + (k0 - 256) + kg);
        half8 bv = *(const half8*)(bRow + k0 + kg);
        __syncthreads();
        *(half8*)(sA + am*40 + kg) = av;
        *(half8*)(sB + am*40 + kg) = bv;
        __syncthreads();
        half8 a0v = *(const half8*)(sA + (wm + lm)*40 + q*8);
        half8 a1v = *(const half8*)(sA + (wm + 16 + lm)*40 + q*8);
        half8 b0v = *(const half8*)(sB + (wn + lm)*40 + q*8);
        half8 b1v = *(const half8*)(sB + (wn + 16 + lm)*40 + q*8);
        acc00 = MFMA16(a0v, b0v, acc00); acc01 = MFMA16(a0v, b1v, acc01);
        acc10 = MFMA16(a1v, b0v, acc10); acc11 = MFMA16(a1v, b1v, acc11);
    }
    int rb = m0 + wm + q*4, col = n0 + wn + lm;
    #pragma unroll
    for (int r = 0; r < 4; ++r) {
        ff[(size_t)(rb + r)*H_ + col]           = acc00[r];
        ff[(size_t)(rb + r)*H_ + col + 16]      = acc01[r];
        ff[(size_t)(rb + 16 + r)*H_ + col]      = acc10[r];
        ff[(size_t)(rb + 16 + r)*H_ + col + 16] = acc11[r];
    }
}

// out[b] = (tanh(ff[b]) + tanh(ff[b+512])) @ U + b_out     grid 32
__global__ __launch_bounds__(256) void k_final_out(const float* __restrict__ ff,
    const float* __restrict__ U, const float* __restrict__ b_out, float* __restrict__ out)
{
    __shared__ float sTh[16*256];
    __shared__ float sU[512];
    const int tid = threadIdx.x;
    const int b0 = blockIdx.x*16;
    sU[tid] = U[tid]; sU[256 + tid] = U[256 + tid];
    for (int idx = tid; idx < 16*256; idx += 256) {
        int r = idx >> 8, h = idx & 255;
        sTh[idx] = fast_tanh(ff[(size_t)(b0 + r)*256 + h]) + fast_tanh(ff[(size_t)(b0 + r + 512)*256 + h]);
    }
    __syncthreads();
    const int wv = tid >> 6, lane = tid & 63;
    for (int r = wv; r < 16; r += 4) {
        float p0 = 0.f, p1 = 0.f;
        #pragma unroll
        for (int k = 0; k < 4; ++k) {
            int h = lane*4 + k;
            float v = sTh[r*256 + h];
            p0 += v * sU[h*2];
            p1 += v * sU[h*2 + 1];
        }
        #pragma unroll
        for (int off = 32; off > 0; off >>= 1) { p0 += __shfl_down(p0, off); p1 += __shfl_down(p1, off); }
        if (lane == 0) {
            out[(b0 + r)*2]     = p0 + b_out[0];
            out[(b0 + r)*2 + 1] = p1 + b_out[1];
        }
    }
}

// ---------------------------------------------------------------- launcher (8 launches)
extern "C" void kernel_launch(void* const* d_in, const int* in_sizes, int n_in,
                              void* d_out, int out_size, void* d_ws, size_t ws_size,
                              hipStream_t stream)
{
    (void)in_sizes; (void)n_in; (void)out_size; (void)ws_size;
    const float* E    = (const float*)d_in[0];
    const float* Wx1  = (const float*)d_in[1];
    const float* Wh1  = (const float*)d_in[2];
    const float* b1   = (const float*)d_in[3];
    const float* Wx2  = (const float*)d_in[4];
    const float* Wh2  = (const float*)d_in[5];
    const float* b2   = (const float*)d_in[6];
    const float* W_y  = (const float*)d_in[7];
    const float* Wh_a = (const float*)d_in[8];
    const float* Wr_a = (const float*)d_in[9];
    const float* w_a  = (const float*)d_in[10];
    const float* Wt_a = (const float*)d_in[11];
    const float* Wp_a = (const float*)d_in[12];
    const float* Wxa  = (const float*)d_in[13];
    const float* U    = (const float*)d_in[14];
    const float* b_o  = (const float*)d_in[15];
    const int* in1 = (const int*)d_in[16];
    const int* in2 = (const int*)d_in[17];
    const int* s1  = (const int*)d_in[18];
    const int* s2  = (const int*)d_in[19];
    float* out = (float*)d_out;

    char* p = (char*)d_ws;
    auto alloc = [&](size_t bytes) { char* r = p; p += (bytes + 255) & ~(size_t)255; return r; };
    _Float16* X16   = (_Float16*)alloc((size_t)BT*L_*KX*2);   // 39.3 MB
    _Float16* Y16   = (_Float16*)alloc(2ull*BT*L_*H_*2);      // 62.9 MB
    _Float16* WyY16 = (_Float16*)alloc((size_t)BT*L_*H_*2);   // 31.5 MB
    _Float16* TH16  = (_Float16*)alloc((size_t)BT*L_*H_*2);   // 31.5 MB
    _Float16* BcatT = (_Float16*)alloc(2ull*NG*KL*2);         // 2.36 MB
    _Float16* AW    = (_Float16*)alloc(393216ull*2);          // 0.79 MB
    _Float16* h2    = (_Float16*)alloc((size_t)BT*H_*2);      // 0.5 MB
    _Float16* rL16  = (_Float16*)alloc((size_t)BT*H_*2);      // 0.5 MB
    float*    ff    = (float*)   alloc((size_t)BT*H_*4);      // 1 MB

    _Float16* WfinT = AW + 262144;

    k_gather<<<9600, 256, 0, stream>>>(E, in1, in2, X16);
    k_prep_lstmW<<<4608, 256, 0, stream>>>(Wx1, Wh1, Wx2, Wh2, BcatT);
    k_prep_attnW<<<1536, 256, 0, stream>>>(W_y, Wh_a, Wr_a, Wt_a, Wp_a, Wxa, AW);

    k_lstm_mega<<<128, 256, 0, stream>>>(X16, BcatT, b1, b2, s1, s2, Y16, h2);
    k_wyyth<<<dim3(4, 960, 2), 256, 0, stream>>>(Y16, AW, WyY16, TH16);
    k_attn_mega<<<128, 256, 0, stream>>>(Y16, WyY16, TH16, AW, w_a, rL16, s1, s2);

    k_final_gemm<<<dim3(4, 16), 256, 0, stream>>>(rL16, h2, WfinT, ff);
    k_final_out<<<32, 256, 0, stream>>>(ff, U, b_o, out);
}

// Round 4
// 2980.671 us; speedup vs baseline: 2.0150x; 2.0150x over previous
//
#include <hip/hip_runtime.h>
#include <cstdint>
#include <cstddef>

// Problem constants
#define B_  512
#define L_  60
#define D_  300
#define H_  256
#define BT  1024          // combined batch (2 branches)
#define KX  320           // D padded to 320 (zeros in pad)
#define KL  576           // LSTM GEMM K: 320 (x) + 256 (h)
#define NG  1024          // 4*H gate width

typedef _Float16 half8   __attribute__((ext_vector_type(8)));
typedef _Float16 half4_t __attribute__((ext_vector_type(4)));
typedef float    floatx4 __attribute__((ext_vector_type(4)));

__device__ __forceinline__ float fast_tanh(float x){ float e = __expf(2.f*x); return 1.f - 2.f/(e + 1.f); }
__device__ __forceinline__ float sigm(float x){ return 1.f/(1.f + __expf(-x)); }

#define MFMA16(a,b,c) __builtin_amdgcn_mfma_f32_16x16x32_f16(a,b,c,0,0,0)

// ---------------------------------------------------------------- prep
// Gather embeddings for [input1; input2] -> X16[1024][60][320] f16 (pad zeros)
__global__ __launch_bounds__(256) void k_gather(const float* __restrict__ E,
    const int* __restrict__ in1, const int* __restrict__ in2, _Float16* __restrict__ X16)
{
    int gid = blockIdx.x*256 + threadIdx.x;
    int row = gid / (L_*40);
    int rem = gid - row*(L_*40);
    int t  = rem / 40;
    int ch = rem - t*40;
    int k0 = ch*8;
    int tok = (row < B_) ? in1[row*L_ + t] : in2[(row - B_)*L_ + t];
    const float* src = E + (size_t)tok*D_ + k0;
    half8 out;
    #pragma unroll
    for (int k = 0; k < 8; ++k) out[k] = (_Float16)0.f;
    if (k0 + 8 <= D_) {
        float4 a = *(const float4*)(src);
        float4 b = *(const float4*)(src + 4);
        out[0]=(_Float16)a.x; out[1]=(_Float16)a.y; out[2]=(_Float16)a.z; out[3]=(_Float16)a.w;
        out[4]=(_Float16)b.x; out[5]=(_Float16)b.y; out[6]=(_Float16)b.z; out[7]=(_Float16)b.w;
    } else if (k0 < D_) {
        float4 a = *(const float4*)(src);
        out[0]=(_Float16)a.x; out[1]=(_Float16)a.y; out[2]=(_Float16)a.z; out[3]=(_Float16)a.w;
    }
    *(half8*)(X16 + ((size_t)row*L_ + t)*KX + k0) = out;
}

// LSTM weights -> BcatT[set][n=1024][k=576] f16; k<300 Wx, 300..319 zero, >=320 Wh
__global__ __launch_bounds__(256) void k_prep_lstmW(const float* __restrict__ Wx1, const float* __restrict__ Wh1,
    const float* __restrict__ Wx2, const float* __restrict__ Wh2, _Float16* __restrict__ BcatT)
{
    int idx = blockIdx.x*256 + threadIdx.x;
    int set = (idx >= KL*NG) ? 1 : 0;
    int rem = idx - set*(KL*NG);
    int k = rem >> 10, n = rem & 1023;
    const float* Wx = set ? Wx2 : Wx1;
    const float* Wh = set ? Wh2 : Wh1;
    float v = 0.f;
    if (k < D_)       v = Wx[k*NG + n];
    else if (k >= KX) v = Wh[(k - KX)*NG + n];
    BcatT[((size_t)set*NG + n)*KL + k] = (_Float16)v;
}

// Attention weights f16 transposed [n][k].
// AW elem offsets: WyT@0 [256][256], WhaT@65536 [256][256],
//   WrtT@131072 [512][256] (n<256: Wr_a col n; else Wt_a col n-256),
//   WfinT@262144 [256][512] (k<256 Wp_a else Wxa). grid 1536.
__global__ __launch_bounds__(256) void k_prep_attnW(const float* __restrict__ W_y,
    const float* __restrict__ Wh_a, const float* __restrict__ Wr_a, const float* __restrict__ Wt_a,
    const float* __restrict__ Wp_a, const float* __restrict__ Wxa, _Float16* __restrict__ AW)
{
    int idx = blockIdx.x*256 + threadIdx.x;
    float v; int dst;
    if (idx < 65536) {
        int k = idx >> 8, n = idx & 255;
        v = W_y[k*256 + n];
        dst = n*256 + k;
    } else if (idx < 131072) {
        int j = idx - 65536; int k = j >> 8, n = j & 255;
        v = Wh_a[k*256 + n];
        dst = 65536 + n*256 + k;
    } else if (idx < 262144) {
        int j = idx - 131072; int n = j >> 8, k = j & 255;
        v = (n < 256) ? Wr_a[k*256 + n] : Wt_a[k*256 + (n - 256)];
        dst = 131072 + n*256 + k;
    } else {
        int j = idx - 262144; int n = j >> 9, k = j & 511;
        v = (k < 256) ? Wp_a[k*256 + n] : Wxa[(k - 256)*256 + n];
        dst = 262144 + n*512 + k;
    }
    AW[dst] = (_Float16)v;
}

// ---------------------------------------------------------------- LSTM step
// grid (ht=16, mt=32) = 512 blocks, 256 thr. Tile 64 rows x 64 gate-cols,
// K=576 split across wave pairs (waves 0-1: k<288, waves 2-3: k>=288).
// B-fragments load direct global->reg (L2-hot); A staged per chunk in LDS.
// Epilogue: LDS-reduce the two K-halves, fused cell update.
// t==0: c_old=0 and h-chunks zero-stuffed (no zero-init launches needed).
__global__ __launch_bounds__(256) void k_lstm_step(
    const _Float16* __restrict__ X16, _Float16* __restrict__ h16,
    float* __restrict__ c, _Float16* __restrict__ Y16,
    const _Float16* __restrict__ BcatT,
    const float* __restrict__ b1, const float* __restrict__ b2,
    const int* __restrict__ s1, const int* __restrict__ s2, int t)
{
    __shared__ float sG[2][64][65];            // 33.3 KB; unions with sA
    _Float16* sA = (_Float16*)sG;              // [2][64][40]

    const int tid = threadIdx.x;
    const int ht = blockIdx.x;                 // 0..15 : h-dims [ht*16, ht*16+16)
    const int mt = blockIdx.y;                 // 0..31 : rows [mt*64, mt*64+64)
    const int set = mt >> 4;
    const int m0 = mt*64;
    const int lane = tid & 63, wv = tid >> 6;
    const int kh = wv >> 1;                    // K-half owned by this wave
    const int wn = (wv & 1)*32;                // col offset within 64
    const int q = lane >> 4, lm = lane & 15;
    const int p_in = t & 1, p_out = (t + 1) & 1;
    const _Float16* hin  = h16 + (size_t)(set*2 + p_in)*BT*H_;
    _Float16*       hout = h16 + (size_t)(set*2 + p_out)*BT*H_;

    // A staging: thread -> (row amA, k-seg kgA), one half8 per K-half tile
    const int amA = tid >> 2, kgA = (tid & 3)*8;
    const int rsA = (m0 + amA) & 1023;
    const int xrowA = set ? ((rsA + 512) & 1023) : rsA;
    const _Float16* aX = X16 + ((size_t)xrowA*L_ + t)*KX;
    const _Float16* aH = hin + (size_t)rsA*H_;

    // B direct: col c = wn + ti*16 + lm -> gate (c>>4), n = (c>>4)*256 + ht*16 + lm
    const _Float16* Bp = BcatT + ((size_t)set*NG + ht*16 + lm)*KL + kh*288 + q*8;
    const int cb = wn >> 4;                    // 0 or 2

    half8 zero8;
    #pragma unroll
    for (int k = 0; k < 8; ++k) zero8[k] = (_Float16)0.f;

    auto loadA0 = [&](int i) -> half8 {        // k-half 0: all x (k<288)
        return *(const half8*)(aX + i*32 + kgA);
    };
    auto loadA1 = [&](int i) -> half8 {        // k-half 1: k = 288..575
        int k1 = 288 + i*32 + kgA;
        if (k1 < KX) return *(const half8*)(aX + k1);
        return (t > 0) ? *(const half8*)(aH + (k1 - KX)) : zero8;
    };

    floatx4 acc[4][2];
    #pragma unroll
    for (int mi = 0; mi < 4; ++mi)
        #pragma unroll
        for (int ti = 0; ti < 2; ++ti) acc[mi][ti] = (floatx4){0.f,0.f,0.f,0.f};

    half8 a0 = loadA0(0), a1 = loadA1(0);
    half8 bp0 = *(const half8*)(Bp + (size_t)cb*256*KL);
    half8 bp1 = *(const half8*)(Bp + (size_t)(cb+1)*256*KL);

    for (int i = 0; i < 9; ++i) {
        __syncthreads();
        *(half8*)(sA + (     amA)*40 + kgA) = a0;
        *(half8*)(sA + (64 + amA)*40 + kgA) = a1;
        __syncthreads();
        half8 b0 = bp0, b1v = bp1;
        if (i < 8) {
            a0 = loadA0(i+1); a1 = loadA1(i+1);
            bp0 = *(const half8*)(Bp + (size_t)cb*256*KL + (i+1)*32);
            bp1 = *(const half8*)(Bp + (size_t)(cb+1)*256*KL + (i+1)*32);
        }
        half8 af[4];
        #pragma unroll
        for (int mi = 0; mi < 4; ++mi)
            af[mi] = *(const half8*)(sA + (kh*64 + mi*16 + lm)*40 + q*8);
        #pragma unroll
        for (int mi = 0; mi < 4; ++mi) {
            acc[mi][0] = MFMA16(af[mi], b0,  acc[mi][0]);
            acc[mi][1] = MFMA16(af[mi], b1v, acc[mi][1]);
        }
    }

    __syncthreads();   // staging reads done; reuse as sG
    #pragma unroll
    for (int mi = 0; mi < 4; ++mi)
        #pragma unroll
        for (int ti = 0; ti < 2; ++ti)
            #pragma unroll
            for (int r = 0; r < 4; ++r)
                sG[kh][mi*16 + q*4 + r][wn + ti*16 + lm] = acc[mi][ti][r];
    __syncthreads();

    const float* bias = set ? b2 : b1;
    for (int idx = tid; idx < 1024; idx += 256) {
        int row = idx & 63, hh = idx >> 6;      // hh 0..15
        int gr = m0 + row;
        int rs = gr & 1023;
        int h = ht*16 + hh;
        float gi = sG[0][row][     hh] + sG[1][row][     hh] + bias[h];
        float gj = sG[0][row][16 + hh] + sG[1][row][16 + hh] + bias[256 + h];
        float gf = sG[0][row][32 + hh] + sG[1][row][32 + hh] + bias[512 + h];
        float go = sG[0][row][48 + hh] + sG[1][row][48 + hh] + bias[768 + h];
        int sl = (set == 0) ? ((rs < B_) ? s1[rs] : s2[rs - B_])
                            : ((rs < B_) ? s2[rs] : s1[rs - B_]);
        size_t ci = (size_t)gr*H_ + h;
        float c_old = (t == 0) ? 0.f : c[ci];
        float c_new = c_old*sigm(gf + 1.f) + sigm(gi)*fast_tanh(gj);
        float h_new = fast_tanh(c_new)*sigm(go);
        bool act = (t < sl);
        float h_old = (t == 0) ? 0.f : (float)hin[(size_t)rs*H_ + h];
        c[ci] = act ? c_new : c_old;
        hout[(size_t)rs*H_ + h] = (_Float16)(act ? h_new : h_old);
        Y16[((size_t)gr*L_ + t)*H_ + h] = act ? (_Float16)h_new : (_Float16)0.f;
    }
}

// ---------------------------------------------------------------- WyY / TH precompute
// z=0: WyY = Y16[set0] @ WyT ; z=1: TH = Y16[set1] @ WhaT. M=61440, N=256, K=256.
__global__ __launch_bounds__(256) void k_wyyth(const _Float16* __restrict__ Y16,
    const _Float16* __restrict__ AW, _Float16* __restrict__ WyY16, _Float16* __restrict__ TH16)
{
    __shared__ _Float16 sA[64*40];
    __shared__ _Float16 sB[64*40];
    const int tid = threadIdx.x;
    const int n0 = blockIdx.x*64, m0 = blockIdx.y*64, z = blockIdx.z;
    const int lane = tid & 63, wv = tid >> 6;
    const int wm = (wv & 1)*32, wn = (wv >> 1)*32;
    const int q = lane >> 4, lm = lane & 15;
    const int am = tid >> 2, kg = (tid & 3)*8;
    const _Float16* aRow = Y16 + (size_t)z*15728640 + (size_t)(m0 + am)*H_;
    const _Float16* bRow = AW + (size_t)z*65536 + (size_t)(n0 + am)*H_;
    _Float16* dst = z ? TH16 : WyY16;
    floatx4 acc00 = {0.f,0.f,0.f,0.f}, acc01 = acc00, acc10 = acc00, acc11 = acc00;
    half8 av = *(const half8*)(aRow + kg);
    half8 bv = *(const half8*)(bRow + kg);
    for (int ch = 0; ch < 8; ++ch) {
        __syncthreads();
        *(half8*)(sA + am*40 + kg) = av;
        *(half8*)(sB + am*40 + kg) = bv;
        __syncthreads();
        if (ch < 7) {
            av = *(const half8*)(aRow + (ch+1)*32 + kg);
            bv = *(const half8*)(bRow + (ch+1)*32 + kg);
        }
        half8 a0v = *(const half8*)(sA + (wm + lm)*40 + q*8);
        half8 a1v = *(const half8*)(sA + (wm + 16 + lm)*40 + q*8);
        half8 b0v = *(const half8*)(sB + (wn + lm)*40 + q*8);
        half8 b1v = *(const half8*)(sB + (wn + 16 + lm)*40 + q*8);
        acc00 = MFMA16(a0v, b0v, acc00); acc01 = MFMA16(a0v, b1v, acc01);
        acc10 = MFMA16(a1v, b0v, acc10); acc11 = MFMA16(a1v, b1v, acc11);
    }
    int rb = m0 + wm + q*4, col = n0 + wn + lm;
    #pragma unroll
    for (int r = 0; r < 4; ++r) {
        dst[(size_t)(rb + r)*H_ + col]           = (_Float16)acc00[r];
        dst[(size_t)(rb + r)*H_ + col + 16]      = (_Float16)acc01[r];
        dst[(size_t)(rb + 16 + r)*H_ + col]      = (_Float16)acc10[r];
        dst[(size_t)(rb + 16 + r)*H_ + col + 16] = (_Float16)acc11[r];
    }
}

// ---------------------------------------------------------------- fused attention step
// grid 256 blocks x 4 rows, 256 thr. Phase1: rGEMM r@[Wr|Wt] via MFMA (4 real rows
// in 16-row frag; t==0 -> exact zeros, skip). Phase2: sTW = TH + rWr. Phase3: logits
// parallel over 16 l-slots x 4 h-quarter lanes (2-deep quad reduce). Phase4: softmax +
// Y-weighted sum + r update. Per-row dead skip (t>=sCap); block exits if all 4 dead.
__global__ __launch_bounds__(256) void k_attn_step(
    const _Float16* __restrict__ Y16, const _Float16* __restrict__ WyY16,
    const _Float16* __restrict__ TH16, const _Float16* __restrict__ AW,
    const float* __restrict__ w_a, _Float16* __restrict__ r16,
    _Float16* __restrict__ rL16, const int* __restrict__ s1, const int* __restrict__ s2, int t)
{
    __shared__ float sW[4][520];
    __shared__ float sTW[4][264];
    __shared__ float sLog[4][64];
    __shared__ float sAl[4][64];
    __shared__ float sWa[256];
    __shared__ int   sCap[4], sAtt[4];

    const int tid = threadIdx.x;
    const int u0 = blockIdx.x*4;
    const int lane = tid & 63, wv = tid >> 6;
    const int q = lane >> 4, lm = lane & 15;

    if (tid < 4) {
        int u = u0 + tid;
        if (u < B_) { sCap[tid] = s2[u];      sAtt[tid] = s1[u]; }
        else        { sCap[tid] = s1[u - B_]; sAtt[tid] = s2[u - B_]; }
    }
    sWa[tid] = w_a[tid];
    __syncthreads();
    int mc = max(max(sCap[0], sCap[1]), max(sCap[2], sCap[3]));
    if (t >= mc) return;    // uniform exit: nothing to do for this block

    // ---- Phase 1: sW[r][0:256]=r@Wr_a, [256:512]=r@Wt_a
    if (t > 0) {
        const _Float16* WrtT = AW + 131072;
        const _Float16* Bq = WrtT + (size_t)(wv*128 + lm)*256 + q*8;
        const _Float16* rp = r16 + (size_t)(u0 + (lm < 4 ? lm : 3))*H_ + q*8;
        floatx4 acc[8];
        #pragma unroll
        for (int i = 0; i < 8; ++i) acc[i] = (floatx4){0.f,0.f,0.f,0.f};
        for (int ch = 0; ch < 8; ++ch) {
            half8 a = *(const half8*)(rp + ch*32);
            half8 b[8];
            #pragma unroll
            for (int ti = 0; ti < 8; ++ti)
                b[ti] = *(const half8*)(Bq + (size_t)ti*16*256 + ch*32);
            #pragma unroll
            for (int ti = 0; ti < 8; ++ti) acc[ti] = MFMA16(a, b[ti], acc[ti]);
        }
        if (q == 0) {
            #pragma unroll
            for (int ti = 0; ti < 8; ++ti)
                #pragma unroll
                for (int r = 0; r < 4; ++r)
                    sW[r][wv*128 + ti*16 + lm] = acc[ti][r];
        }
    } else {
        for (int i = tid; i < 4*520; i += 256) ((float*)sW)[i] = 0.f;
    }
    __syncthreads();

    // ---- Phase 2: sTW = TH[u][t] + rWr
    for (int i = tid; i < 1024; i += 256) {
        int row = i >> 8, h = i & 255;
        sTW[row][h] = (float)TH16[((size_t)(u0 + row)*L_ + t)*H_ + h] + sW[row][h];
    }
    __syncthreads();

    // ---- Phase 3+4: per-wave row
    const int row = wv;
    if (t < sCap[row]) {
        const int u = u0 + row;
        const int sa = sAtt[row];
        const int lsub = lane >> 2, li = lane & 3;

        // logits: l = lb*16 + lsub ; lane quad li covers h = j*16 + li*4 (+k)
        for (int lb = 0; lb*16 < sa; ++lb) {
            int l = lb*16 + lsub;
            float v = 0.f;
            if (l < sa) {
                const _Float16* wy = WyY16 + ((size_t)u*L_ + l)*H_;
                #pragma unroll
                for (int j = 0; j < 16; ++j) {
                    int h0 = j*16 + li*4;
                    half4_t yv = *(const half4_t*)(wy + h0);
                    #pragma unroll
                    for (int k = 0; k < 4; ++k)
                        v += fast_tanh((float)yv[k] + sTW[row][h0 + k]) * sWa[h0 + k];
                }
            }
            v += __shfl_xor(v, 1);
            v += __shfl_xor(v, 2);
            if (li == 0 && l < sa) sLog[row][l] = v;
        }
        // softmax over l (wave-private)
        {
            float x = (lane < sa) ? sLog[row][lane] : -3.4e38f;
            float m = x;
            #pragma unroll
            for (int off = 32; off > 0; off >>= 1) m = fmaxf(m, __shfl_xor(m, off));
            float e = (lane < sa) ? __expf(x - m) : 0.f;
            float s = e;
            #pragma unroll
            for (int off = 32; off > 0; off >>= 1) s += __shfl_xor(s, off);
            sAl[row][lane] = e / s;
        }
        // r update: lane covers h = lane*4 .. +3
        {
            int h4 = lane*4;
            const _Float16* yb = Y16 + ((size_t)u*L_)*H_ + h4;
            float a0 = 0.f, a1 = 0.f, a2 = 0.f, a3 = 0.f;
            for (int l = 0; l < sa; ++l) {
                float al = sAl[row][l];
                half4_t yv = *(const half4_t*)(yb + (size_t)l*H_);
                a0 += al*(float)yv[0]; a1 += al*(float)yv[1];
                a2 += al*(float)yv[2]; a3 += al*(float)yv[3];
            }
            half4_t outv;
            outv[0] = (_Float16)(a0 + fast_tanh(sW[row][256 + h4]));
            outv[1] = (_Float16)(a1 + fast_tanh(sW[row][257 + h4]));
            outv[2] = (_Float16)(a2 + fast_tanh(sW[row][258 + h4]));
            outv[3] = (_Float16)(a3 + fast_tanh(sW[row][259 + h4]));
            *(half4_t*)(r16 + (size_t)u*H_ + h4) = outv;
            if (t == sCap[row] - 1)
                *(half4_t*)(rL16 + (size_t)u*H_ + h4) = outv;
        }
    }
}

// ---------------------------------------------------------------- ff = [rL | h2] @ (Wp_a|Wxa)
__global__ __launch_bounds__(256) void k_final_gemm(const _Float16* __restrict__ rL16,
    const _Float16* __restrict__ h2, const _Float16* __restrict__ WfinT, float* __restrict__ ff)
{
    __shared__ _Float16 sA[64*40];
    __shared__ _Float16 sB[64*40];
    const int tid = threadIdx.x;
    const int n0 = blockIdx.x*64, m0 = blockIdx.y*64;
    const int lane = tid & 63, wv = tid >> 6;
    const int wm = (wv & 1)*32, wn = (wv >> 1)*32;
    const int q = lane >> 4, lm = lane & 15;
    const int am = tid >> 2, kg = (tid & 3)*8;
    const int row = m0 + am;
    const _Float16* bRow = WfinT + (size_t)(n0 + am)*512;
    floatx4 acc00 = {0.f,0.f,0.f,0.f}, acc01 = acc00, acc10 = acc00, acc11 = acc00;
    for (int ch = 0; ch < 16; ++ch) {
        const int k0 = ch*32;
        half8 av = (k0 < 256) ? *(const half8*)(rL16 + (size_t)row*H_ + k0 + kg)
                              : *(const half8*)(h2   + (size_t)row*H_ + (k0 - 256) + kg);
        half8 bv = *(const half8*)(bRow + k0 + kg);
        __syncthreads();
        *(half8*)(sA + am*40 + kg) = av;
        *(half8*)(sB + am*40 + kg) = bv;
        __syncthreads();
        half8 a0v = *(const half8*)(sA + (wm + lm)*40 + q*8);
        half8 a1v = *(const half8*)(sA + (wm + 16 + lm)*40 + q*8);
        half8 b0v = *(const half8*)(sB + (wn + lm)*40 + q*8);
        half8 b1v = *(const half8*)(sB + (wn + 16 + lm)*40 + q*8);
        acc00 = MFMA16(a0v, b0v, acc00); acc01 = MFMA16(a0v, b1v, acc01);
        acc10 = MFMA16(a1v, b0v, acc10); acc11 = MFMA16(a1v, b1v, acc11);
    }
    int rb = m0 + wm + q*4, col = n0 + wn + lm;
    #pragma unroll
    for (int r = 0; r < 4; ++r) {
        ff[(size_t)(rb + r)*H_ + col]           = acc00[r];
        ff[(size_t)(rb + r)*H_ + col + 16]      = acc01[r];
        ff[(size_t)(rb + 16 + r)*H_ + col]      = acc10[r];
        ff[(size_t)(rb + 16 + r)*H_ + col + 16] = acc11[r];
    }
}

// out[b] = (tanh(ff[b]) + tanh(ff[b+512])) @ U + b_out     grid 32
__global__ __launch_bounds__(256) void k_final_out(const float* __restrict__ ff,
    const float* __restrict__ U, const float* __restrict__ b_out, float* __restrict__ out)
{
    __shared__ float sTh[16*256];
    __shared__ float sU[512];
    const int tid = threadIdx.x;
    const int b0 = blockIdx.x*16;
    sU[tid] = U[tid]; sU[256 + tid] = U[256 + tid];
    for (int idx = tid; idx < 16*256; idx += 256) {
        int r = idx >> 8, h = idx & 255;
        sTh[idx] = fast_tanh(ff[(size_t)(b0 + r)*256 + h]) + fast_tanh(ff[(size_t)(b0 + r + 512)*256 + h]);
    }
    __syncthreads();
    const int wv = tid >> 6, lane = tid & 63;
    for (int r = wv; r < 16; r += 4) {
        float p0 = 0.f, p1 = 0.f;
        #pragma unroll
        for (int k = 0; k < 4; ++k) {
            int h = lane*4 + k;
            float v = sTh[r*256 + h];
            p0 += v * sU[h*2];
            p1 += v * sU[h*2 + 1];
        }
        #pragma unroll
        for (int off = 32; off > 0; off >>= 1) { p0 += __shfl_down(p0, off); p1 += __shfl_down(p1, off); }
        if (lane == 0) {
            out[(b0 + r)*2]     = p0 + b_out[0];
            out[(b0 + r)*2 + 1] = p1 + b_out[1];
        }
    }
}

// ---------------------------------------------------------------- launcher (126 launches)
extern "C" void kernel_launch(void* const* d_in, const int* in_sizes, int n_in,
                              void* d_out, int out_size, void* d_ws, size_t ws_size,
                              hipStream_t stream)
{
    (void)in_sizes; (void)n_in; (void)out_size; (void)ws_size;
    const float* E    = (const float*)d_in[0];
    const float* Wx1  = (const float*)d_in[1];
    const float* Wh1  = (const float*)d_in[2];
    const float* b1   = (const float*)d_in[3];
    const float* Wx2  = (const float*)d_in[4];
    const float* Wh2  = (const float*)d_in[5];
    const float* b2   = (const float*)d_in[6];
    const float* W_y  = (const float*)d_in[7];
    const float* Wh_a = (const float*)d_in[8];
    const float* Wr_a = (const float*)d_in[9];
    const float* w_a  = (const float*)d_in[10];
    const float* Wt_a = (const float*)d_in[11];
    const float* Wp_a = (const float*)d_in[12];
    const float* Wxa  = (const float*)d_in[13];
    const float* U    = (const float*)d_in[14];
    const float* b_o  = (const float*)d_in[15];
    const int* in1 = (const int*)d_in[16];
    const int* in2 = (const int*)d_in[17];
    const int* s1  = (const int*)d_in[18];
    const int* s2  = (const int*)d_in[19];
    float* out = (float*)d_out;

    char* p = (char*)d_ws;
    auto alloc = [&](size_t bytes) { char* r = p; p += (bytes + 255) & ~(size_t)255; return r; };
    _Float16* X16   = (_Float16*)alloc((size_t)BT*L_*KX*2);   // 39.3 MB
    _Float16* Y16   = (_Float16*)alloc(2ull*BT*L_*H_*2);      // 62.9 MB
    _Float16* WyY16 = (_Float16*)alloc((size_t)BT*L_*H_*2);   // 31.5 MB
    _Float16* TH16  = (_Float16*)alloc((size_t)BT*L_*H_*2);   // 31.5 MB
    _Float16* BcatT = (_Float16*)alloc(2ull*NG*KL*2);         // 2.36 MB
    _Float16* AW    = (_Float16*)alloc(393216ull*2);          // 0.79 MB
    _Float16* h16   = (_Float16*)alloc(4ull*BT*H_*2);         // 2 MB  [set][parity]
    float*    c     = (float*)   alloc(2ull*BT*H_*4);         // 2 MB
    _Float16* r16   = (_Float16*)alloc((size_t)BT*H_*2);
    _Float16* rL16  = (_Float16*)alloc((size_t)BT*H_*2);
    float*    ff    = (float*)   alloc((size_t)BT*H_*4);

    _Float16* WfinT = AW + 262144;

    k_gather<<<9600, 256, 0, stream>>>(E, in1, in2, X16);
    k_prep_lstmW<<<4608, 256, 0, stream>>>(Wx1, Wh1, Wx2, Wh2, BcatT);
    k_prep_attnW<<<1536, 256, 0, stream>>>(W_y, Wh_a, Wr_a, Wt_a, Wp_a, Wxa, AW);

    for (int t = 0; t < L_; ++t)
        k_lstm_step<<<dim3(16, 32), 256, 0, stream>>>(X16, h16, c, Y16, BcatT, b1, b2, s1, s2, t);

    k_wyyth<<<dim3(4, 960, 2), 256, 0, stream>>>(Y16, AW, WyY16, TH16);

    for (int t = 0; t < L_; ++t)
        k_attn_step<<<256, 256, 0, stream>>>(Y16, WyY16, TH16, AW, w_a, r16, rL16, s1, s2, t);

    _Float16* h2f = h16 + 2ull*BT*H_;   // set1, parity 0 (after t=59)
    k_final_gemm<<<dim3(4, 16), 256, 0, stream>>>(rL16, h2f, WfinT, ff);
    k_final_out<<<32, 256, 0, stream>>>(ff, U, b_o, out);
}